// Round 4
// baseline (1414.107 us; speedup 1.0000x reference)
//
#include <hip/hip_runtime.h>

typedef _Float16 half8 __attribute__((ext_vector_type(8)));
typedef float f32x4 __attribute__((ext_vector_type(4)));

// Block = 512 threads (8 waves). LDS holds ALL of W1 as fp16 in MFMA B-fragment
// order: frag(e,kt,nt) = 64 lanes x 8 halfs, lane l's half8 at byte l*16 ->
// ds_read_b128 with linear lane addresses (2-way bank alias = free).
// Each wave owns a 32-atom tile (grid-stride), keeps A-frags in regs, and
// runs the e-loop 0..3 reusing them; epilogue per atom is exec-masked on
// zidx==e. 64KB LDS * 2 blocks/CU + <=128 VGPR -> 4 waves/SIMD.
__global__ __launch_bounds__(512, 4)
void elemental_atomwise_kernel(const float* __restrict__ x,
                               const int* __restrict__ zidx,
                               const int* __restrict__ idx_m,
                               const float* __restrict__ W1,
                               const float* __restrict__ b1,
                               const float* __restrict__ W2,
                               const float* __restrict__ b2,
                               float* __restrict__ y,
                               int N, int ntiles) {
  __shared__ _Float16 w1s[32768];  // 64 frags x 64 lanes x 8 halfs = 64 KB

  // ---- stage W1 fp32 [4][128][64] -> swizzled fp16 frag blob (once per block) ----
#pragma unroll
  for (int it = 0; it < 16; ++it) {
    int idx4 = threadIdx.x + it * 512;       // f32x4 index 0..8191
    f32x4 v = ((const f32x4*)W1)[idx4];
    int lin = idx4 << 2;                     // e*8192 + k*64 + h
    int e = lin >> 13;
    int k = (lin >> 6) & 127;
    int h0 = lin & 63;                       // multiple of 4, same nt for all 4
    int kt = k >> 5, kq = (k >> 3) & 3, j = k & 7;
    int nt = h0 >> 4;
    int fb = ((e * 4 + kt) * 4 + nt) * 512 + kq * 128 + j;  // + c*8 below
#pragma unroll
    for (int jj = 0; jj < 4; ++jj)
      w1s[fb + ((h0 + jj) & 15) * 8] = (_Float16)v[jj];
  }
  __syncthreads();

  const int lane = threadIdx.x & 63;
  const int wv = threadIdx.x >> 6;  // 0..7
  const int c = lane & 15;
  const int q = lane >> 4;

  // loop-invariant epilogue params (per lane: indexed by hidden col c)
  float b1v[4][4], w2v[4][4], b2v[4];
#pragma unroll
  for (int e = 0; e < 4; ++e) {
    b2v[e] = b2[e];
#pragma unroll
    for (int nt = 0; nt < 4; ++nt) {
      b1v[e][nt] = b1[e * 64 + nt * 16 + c];
      w2v[e][nt] = W2[e * 64 + nt * 16 + c];
    }
  }

  for (int t = blockIdx.x * 8 + wv; t < ntiles; t += gridDim.x * 8) {
    const long base = (long)t * 32;

    long mi = base + (lane & 31);
    if (mi >= N) mi = N - 1;
    const int zvec = zidx[mi];
    const int ivec = idx_m[mi];

    // ---- A frags: lane holds row m = base + mt*16 + c, k = kt*32 + q*8 + j ----
    half8 af[2][4];
#pragma unroll
    for (int mt = 0; mt < 2; ++mt) {
      long row = base + mt * 16 + c;
      if (row >= N) row = N - 1;
      const f32x4* rp = (const f32x4*)(x + row * 128);
#pragma unroll
      for (int kt = 0; kt < 4; ++kt) {
        f32x4 u0 = rp[kt * 8 + q * 2];
        f32x4 u1 = rp[kt * 8 + q * 2 + 1];
        half8 a;
        a[0] = (_Float16)u0[0]; a[1] = (_Float16)u0[1];
        a[2] = (_Float16)u0[2]; a[3] = (_Float16)u0[3];
        a[4] = (_Float16)u1[0]; a[5] = (_Float16)u1[1];
        a[6] = (_Float16)u1[2]; a[7] = (_Float16)u1[3];
        af[mt][kt] = a;
      }
    }

#pragma unroll
    for (int e = 0; e < 4; ++e) {
      f32x4 acc[2][4];
#pragma unroll
      for (int mt = 0; mt < 2; ++mt)
#pragma unroll
        for (int nt = 0; nt < 4; ++nt)
          acc[mt][nt] = (f32x4){0.f, 0.f, 0.f, 0.f};

#pragma unroll
      for (int kt = 0; kt < 4; ++kt) {
#pragma unroll
        for (int nt = 0; nt < 4; ++nt) {
          half8 bf = *(const half8*)&w1s[((e * 4 + kt) * 4 + nt) * 512 + lane * 8];
#pragma unroll
          for (int mt = 0; mt < 2; ++mt)
            acc[mt][nt] = __builtin_amdgcn_mfma_f32_16x16x32_f16(
                af[mt][kt], bf, acc[mt][nt], 0, 0, 0);
        }
      }

      // ---- epilogue: exec-masked on zm==e; ssp + W2-dot + 16-lane butterfly ----
#pragma unroll
      for (int mt = 0; mt < 2; ++mt) {
#pragma unroll
        for (int i = 0; i < 4; ++i) {
          const int mloc = mt * 16 + q * 4 + i;       // atom within 32-tile
          const int zm = __shfl(zvec, mloc);
          const int im = __shfl(ivec, mloc);
          if (zm == e) {
            float s = 0.0f;
#pragma unroll
            for (int nt = 0; nt < 4; ++nt) {
              float tt = acc[mt][nt][i] + b1v[e][nt];
              float sp = __logf(1.0f + __expf(tt)) - 0.69314718056f;  // ssp
              s = fmaf(sp, w2v[e][nt], s);
            }
            s += __shfl_xor(s, 1);
            s += __shfl_xor(s, 2);
            s += __shfl_xor(s, 4);
            s += __shfl_xor(s, 8);
            if (c == 0 && base + mloc < N)
              atomicAdd(&y[im], s + b2v[e]);
          }
        }
      }
    }
  }
}

extern "C" void kernel_launch(void* const* d_in, const int* in_sizes, int n_in,
                              void* d_out, int out_size, void* d_ws, size_t ws_size,
                              hipStream_t stream) {
  const float* x = (const float*)d_in[0];
  const int* zidx = (const int*)d_in[1];
  const int* idx_m = (const int*)d_in[2];
  const float* W1 = (const float*)d_in[3];
  const float* b1 = (const float*)d_in[4];
  const float* W2 = (const float*)d_in[5];
  const float* b2 = (const float*)d_in[6];
  float* y = (float*)d_out;

  const int N = in_sizes[0] / 128;
  const int ntiles = (N + 31) / 32;  // 32-atom tiles

  // y accumulated with atomics: zero it first (d_out is poisoned 0xAA)
  (void)hipMemsetAsync(d_out, 0, (size_t)out_size * sizeof(float), stream);

  int blocks = 512;  // 2 blocks/CU; each block = 8 waves grid-striding tiles
  int maxb = (ntiles + 7) / 8;
  if (blocks > maxb) blocks = maxb;

  elemental_atomwise_kernel<<<blocks, 512, 0, stream>>>(
      x, zidx, idx_m, W1, b1, W2, b2, y, N, ntiles);
}